// Round 16
// baseline (408.734 us; speedup 1.0000x reference)
//
#include <hip/hip_runtime.h>
#include <hip/hip_bf16.h>

#define B_ 4096
#define T_ 128
#define F_ 64
#define H_ 32
#define G_ 128  // 4*H

using short8 = __attribute__((ext_vector_type(8))) short;
using f32x4  = __attribute__((ext_vector_type(4))) float;
using uint4v = __attribute__((ext_vector_type(4))) unsigned int;

#define MFMA16(Af, Bf, Cf) __builtin_amdgcn_mfma_f32_16x16x32_bf16((Af), (Bf), (Cf), 0, 0, 0)

__device__ __forceinline__ float sigmoid_f(float z) {
    return __builtin_amdgcn_rcpf(1.0f + __expf(-z));
}
__device__ __forceinline__ unsigned short bfb(float f) {
    return __builtin_bit_cast(unsigned short, __float2bfloat16(f));
}
__device__ __forceinline__ unsigned int pk(float a, float b) {
    return (unsigned int)bfb(a) | ((unsigned int)bfb(b) << 16);
}

// lgkm-only barrier: ds_write visible to other waves, NO vmcnt drain (x-loads and
// out-stores free-run across it). sched_barrier(0) pins the following ds_read below.
#define XBAR()                                                  \
    {                                                           \
        asm volatile("s_waitcnt lgkmcnt(0)" ::: "memory");      \
        __builtin_amdgcn_s_barrier();                           \
        __builtin_amdgcn_sched_barrier(0);                      \
    }

// TRUE 4-WAY HOMOGENEOUS SPLIT of the transposed recurrence (p-map validated r6-r12).
//   lane = 16g + c: c = batch col, D rows = gate idx 16n+4g+r. p(g,i)=4g+(i&3)+16(i>>2).
// Wave w: hw = w>>1 (hidden half -> tiles n = 2q+hw), rsel = w&1 (acc rows 2rsel,2rsel+1).
//   Per step: 4 z-MFMAs (x2-redundant between pair waves — MFMA pipe is per-SIMD, cheap)
//   -> 6 sigmoids (vs 12 in r7) for hidden j = 16hw+4g+{2rsel,2rsel+1} -> pack 1 dword.
// Exchange: write hx[buf][c*20 + 4g + w]; b128 read at c*20+4g gives dword w = elems
//   (2w,2w+1) = h[16(w>>1)+4g+2(w&1)+{0,1}] == p-map exactly -> hfrag, NO assemble ops.
// Encoder hides the ds_read under next-step x-cvt + We-MFMAs (safe: no vmcnt drain);
// decoder pipelines out-proj of h_{t-1} into the window. Gate math bit-identical to r7.
extern "C" __global__ __launch_bounds__(256, 1)
void lstm_ae(const float* __restrict__ x,
             const float* __restrict__ We,
             const float* __restrict__ Ue,
             const float* __restrict__ be,
             const float* __restrict__ Wd,
             const float* __restrict__ Ud,
             const float* __restrict__ bd,
             const float* __restrict__ Wout,
             const float* __restrict__ bout,
             float* __restrict__ out)
{
    const int lane = threadIdx.x & 63;
    const int w    = threadIdx.x >> 6;   // 0..3
    const int hw   = w >> 1;             // tile set: n = 2q + hw
    const int rsel = w & 1;              // acc row pair {2rsel, 2rsel+1}
    const int g    = lane >> 4;
    const int c    = lane & 15;
    const int b0   = blockIdx.x << 4;

    // exchange: [buf][c*20 + (4g + w)]; stride 20 dwords -> b128 reads 16B-aligned
    __shared__ __align__(16) unsigned int hx[2][16 * 20];

    // ---------------- encoder weights: tiles n = 2q + hw ----------------
    short8 weF[4][2];   // We^T: K=64 -> 2 chunks, natural k-map 8g+i
    short8 ueF[4];      // Ue^T: K=32, p-map
    f32x4  beC[4];
#pragma unroll
    for (int q = 0; q < 4; ++q) {
        const int n = 2 * q + hw;
#pragma unroll
        for (int kc = 0; kc < 2; ++kc)
#pragma unroll
            for (int i = 0; i < 8; ++i)
                weF[q][kc][i] = (short)bfb(We[(kc * 32 + 8 * g + i) * G_ + 16 * n + c]);
#pragma unroll
        for (int i = 0; i < 8; ++i)
            ueF[q][i] = (short)bfb(Ue[(4 * g + (i & 3) + 16 * (i >> 2)) * G_ + 16 * n + c]);
        beC[q] = *(const f32x4*)(be + 16 * n + 4 * g);
    }

    const float* xr = x + (size_t)(b0 + c) * (T_ * F_);
    const int xo = 8 * g;

    short8 hfrag = (short8)0;
    float cs0 = 0.f, cs1 = 0.f;   // cell state: hidden 16hw+4g+2rsel+{0,1}, batch c

#define CVTX(xf0, xf1)                                   \
    {                                                    \
        _Pragma("unroll")                                \
        for (int i = 0; i < 4; ++i) {                    \
            xf0[i]     = (short)bfb(xa[i]);              \
            xf0[4 + i] = (short)bfb(xb[i]);              \
            xf1[i]     = (short)bfb(xc[i]);              \
            xf1[4 + i] = (short)bfb(xd[i]);              \
        }                                                \
    }

    // gates for 2 static rows (rule #20: no runtime vector index). acc[0..3]=i,f,g,o.
#define GATES2(R0, R1)                                   \
    {                                                    \
        float iv0 = sigmoid_f(acc[0][R0]);               \
        float fv0 = sigmoid_f(acc[1][R0]);               \
        float gv0 = fmaxf(acc[2][R0], 0.f);              \
        float ov0 = sigmoid_f(acc[3][R0]);               \
        float cc0 = fmaf(fv0, cs0, iv0 * gv0);           \
        cs0 = cc0;                                       \
        float h0 = ov0 * fmaxf(cc0, 0.f);                \
        float iv1 = sigmoid_f(acc[0][R1]);               \
        float fv1 = sigmoid_f(acc[1][R1]);               \
        float gv1 = fmaxf(acc[2][R1], 0.f);              \
        float ov1 = sigmoid_f(acc[3][R1]);               \
        float cc1 = fmaf(fv1, cs1, iv1 * gv1);           \
        cs1 = cc1;                                       \
        float h1 = ov1 * fmaxf(cc1, 0.f);                \
        hword = pk(h0, h1);                              \
    }
#define GATES()  { if (rsel == 0) GATES2(0, 1) else GATES2(2, 3) }

    // ---------------- prologue: acc = bias + x0@We; stage x1 ----------------
    f32x4 xa = *(const f32x4*)(xr + xo);
    f32x4 xb = *(const f32x4*)(xr + xo + 4);
    f32x4 xc = *(const f32x4*)(xr + 32 + xo);
    f32x4 xd = *(const f32x4*)(xr + 36 + xo);
    short8 xf0, xf1;
    CVTX(xf0, xf1)
    {
        const float* xn = xr + F_;
        xa = *(const f32x4*)(xn + xo);
        xb = *(const f32x4*)(xn + xo + 4);
        xc = *(const f32x4*)(xn + 32 + xo);
        xd = *(const f32x4*)(xn + 36 + xo);
    }
    f32x4 acc[4];
#pragma unroll
    for (int q = 0; q < 4; ++q) {
        acc[q] = MFMA16(weF[q][0], xf0, beC[q]);
        acc[q] = MFMA16(weF[q][1], xf1, acc[q]);
    }

    // =============================== encoder scan ===============================
#pragma unroll 1
    for (int t = 0; t < T_; ++t) {
#pragma unroll
        for (int q = 0; q < 4; ++q)
            acc[q] = MFMA16(ueF[q], hfrag, acc[q]);   // z = (bias + x@We) + Ue^T h
        unsigned int hword;
        GATES()
        hx[t & 1][c * 20 + 4 * g + w] = hword;
        XBAR()
        uint4v hb = *(const uint4v*)&hx[t & 1][c * 20 + 4 * g];  // full h_t (p-map)
        if (t + 1 < T_) {   // window filler: next step's x-projection (h-independent)
            CVTX(xf0, xf1)
            if (t + 2 < T_) {
                const float* xn = xr + (t + 2) * F_;
                xa = *(const f32x4*)(xn + xo);
                xb = *(const f32x4*)(xn + xo + 4);
                xc = *(const f32x4*)(xn + 32 + xo);
                xd = *(const f32x4*)(xn + 36 + xo);
            }
#pragma unroll
            for (int q = 0; q < 4; ++q) {
                acc[q] = MFMA16(weF[q][0], xf0, beC[q]);
                acc[q] = MFMA16(weF[q][1], xf1, acc[q]);
            }
        }
        hfrag = __builtin_bit_cast(short8, hb);   // lgkm wait lands here
    }

    // ============ decoder weights + constant input zd = bd + Wd^T hT ============
    short8 udF[4], woF;
    f32x4  zd[4], boC;
    {
        short8 wdF[4];
#pragma unroll
        for (int q = 0; q < 4; ++q) {
            const int n = 2 * q + hw;
#pragma unroll
            for (int i = 0; i < 8; ++i) {
                const int pr = 4 * g + (i & 3) + 16 * (i >> 2);
                wdF[q][i] = (short)bfb(Wd[pr * G_ + 16 * n + c]);
                udF[q][i] = (short)bfb(Ud[pr * G_ + 16 * n + c]);
            }
        }
#pragma unroll
        for (int q = 0; q < 4; ++q) {
            f32x4 tb = *(const f32x4*)(bd + 16 * (2 * q + hw) + 4 * g);
            zd[q] = MFMA16(wdF[q], hfrag, tb);   // hfrag == full hT
        }
        // out-proj: wave w owns feature tile m = w
#pragma unroll
        for (int i = 0; i < 8; ++i)
            woF[i] = (short)bfb(Wout[(4 * g + (i & 3) + 16 * (i >> 2)) * F_ + 16 * w + c]);
        float v = bout[16 * w + c];
        boC[0] = v; boC[1] = v; boC[2] = v; boC[3] = v;
    }

    hfrag = (short8)0;
    cs0 = 0.f; cs1 = 0.f;

    float* ob[4];
#pragma unroll
    for (int r = 0; r < 4; ++r)
        ob[r] = out + (size_t)(b0 + 4 * g + r) * (T_ * F_) + 16 * w + c;

    // ============ decoder scan; out-proj of h_{t-1} pipelined into the window ============
#pragma unroll 1
    for (int t = 0; t < T_; ++t) {
#pragma unroll
        for (int q = 0; q < 4; ++q)
            acc[q] = MFMA16(udF[q], hfrag, zd[q]);   // z = zd + Ud^T h
        unsigned int hword;
        GATES()
        hx[t & 1][c * 20 + 4 * g + w] = hword;
        XBAR()
        uint4v hb = *(const uint4v*)&hx[t & 1][c * 20 + 4 * g];
        if (t > 0) {   // window filler: out-proj of h_{t-1} (current hfrag, pre-overwrite)
            f32x4 oac = MFMA16(hfrag, woF, boC);
#pragma unroll
            for (int r = 0; r < 4; ++r)
                ob[r][(t - 1) * F_] = oac[r];
        }
        hfrag = __builtin_bit_cast(short8, hb);   // full h_t
    }
    // epilogue: out-proj of final h
    {
        f32x4 oac = MFMA16(hfrag, woF, boC);
#pragma unroll
        for (int r = 0; r < 4; ++r)
            ob[r][(T_ - 1) * F_] = oac[r];
    }
}

extern "C" void kernel_launch(void* const* d_in, const int* in_sizes, int n_in,
                              void* d_out, int out_size, void* d_ws, size_t ws_size,
                              hipStream_t stream) {
    (void)in_sizes; (void)n_in; (void)d_ws; (void)ws_size; (void)out_size;
    const float* x    = (const float*)d_in[0];
    const float* We   = (const float*)d_in[1];
    const float* Ue   = (const float*)d_in[2];
    const float* be   = (const float*)d_in[3];
    const float* Wd   = (const float*)d_in[4];
    const float* Ud   = (const float*)d_in[5];
    const float* bd   = (const float*)d_in[6];
    const float* Wout = (const float*)d_in[7];
    const float* bout = (const float*)d_in[8];
    float* out = (float*)d_out;

    dim3 grid(B_ / 16), block(256);
    hipLaunchKernelGGL(lstm_ae, grid, block, 0, stream,
                       x, We, Ue, be, Wd, Ud, bd, Wout, bout, out);
}